// Round 7
// baseline (117.571 us; speedup 1.0000x reference)
//
#include <hip/hip_runtime.h>

#define NN 1024

typedef float f32x8 __attribute__((ext_vector_type(8)));

// ---------------- workspace layout (floats) ----------------
// PH     : [896][1024][8] @ 0        (7340032)  rows>=64 x cols 64..960 NEVER touched
// Uin    : [64][1024][8]  @ 7340032  (524288)
// Utop   : [64][1024][8]  @ 7864320  (524288)
// Urt    : [896][64][8]   @ 8388608  (458752)
// Uout   : [64][1024][8]  @ 8847360  (524288)
// P      : [1024][8]      @ 9371648  (8192)
// GXPin1 : [1024][24]     @ 9379840  gin  over P0
// GXPhid1: [1024][24]     @ 9404416  ghid over P1 (+post0 tail)
// GXPout : [1024][24]     @ 9428992  gout over P2
// GXPin2 : [1024][24]     @ 9453568  gin  over P2
// GXPhid2: [1024][24]     @ 9478144  ghid over P3 (cols 960..)
// Spart  : [56][896][8]   @ 9502720  (401408)  hid1 row-tile partial sums (rt>=4 used)

__device__ __forceinline__ float sigmoid_f(float x)
{
    return __fdividef(1.f, 1.f + __expf(-x));
}
__device__ __forceinline__ float tanh_f(float x)
{
    float ax = fabsf(x);
    float e  = __expf(-2.f * ax);
    float t  = __fdividef(1.f - e, 1.f + e);
    return copysignf(t, x);
}
__device__ __forceinline__ f32x8 ld8(const float* __restrict__ p) { return *(const f32x8*)p; }
__device__ __forceinline__ void st8(float* __restrict__ p, f32x8 v) { *(f32x8*)p = v; }

// gx = sGX[j] (row part) + g{r,z,n}[d] (col part, in regs); gh = sBhh[j] + Whh[j]·h
__device__ __forceinline__ f32x8 gru_core(const float (*__restrict__ sWH)[8],
                                          const float* __restrict__ sGX,
                                          const float* __restrict__ sBhh,
                                          f32x8 gr, f32x8 gz, f32x8 gn,
                                          f32x8 h, float lr)
{
    f32x8 upd;
#pragma unroll
    for (int d = 0; d < 8; ++d) {
        float hr = sBhh[d], hz = sBhh[8 + d], hn = sBhh[16 + d];
#pragma unroll
        for (int k = 0; k < 8; ++k) {
            hr = fmaf(sWH[d][k],      h[k], hr);
            hz = fmaf(sWH[8 + d][k],  h[k], hz);
            hn = fmaf(sWH[16 + d][k], h[k], hn);
        }
        float r  = sigmoid_f(sGX[d] + gr[d] + hr);
        float z  = sigmoid_f(sGX[8 + d] + gz[d] + hz);
        float nv = tanh_f(fmaf(r, hn, sGX[16 + d] + gn[d]));
        float g  = (1.f - z) * nv + z * h[d];
        upd[d] = fmaf(g, lr, h[d]);
    }
    return upd;
}

#define SYN_STAGE(PREROW)                                                               \
    __shared__ float sWH[24][8]; __shared__ float sGX[24]; __shared__ float sBhh[24];   \
    { int t_ = threadIdx.x;                                                             \
      if (t_ < 192) { int j = t_ >> 3, k = t_ & 7; sWH[j][k] = Whh[j * 8 + k]; }        \
      else if (t_ < 216) { int j = t_ - 192;                                            \
        float a = Bih[j] + Wih[j * 17 + 16] * reward[0];                                \
        _Pragma("unroll") for (int k = 0; k < 8; ++k)                                   \
            a = fmaf(Wih[j * 17 + k], P[(PREROW) * 8 + k], a);                          \
        sGX[j] = a; sBhh[j] = Bhh[j]; }                                                 \
      __syncthreads(); }

// P init + GXPin1 (gin over P0) + GXPhid1 tail (ghid over post0, cols 960..)
__global__ void __launch_bounds__(256)
k_prep(const float* __restrict__ obs, const float* __restrict__ fiw,
       const float* __restrict__ fib, const float* __restrict__ post0,
       float* __restrict__ P, float* __restrict__ GXPin1, float* __restrict__ GXPhid1,
       const float* __restrict__ gin_wih, const float* __restrict__ ghid_wih)
{
    int t = threadIdx.x, b = blockIdx.x;
    int gid = b * 256 + t;
    float pv;
    if (gid < 512) {
        int i = gid >> 3, j = gid & 7;
        float rs = 0.f;
#pragma unroll
        for (int d = 0; d < 8; ++d) rs += fiw[j * 8 + d];
        pv = tanhf(obs[i] * rs + fib[j]);
    } else {
        pv = post0[gid];
    }
    P[gid] = pv;
    __shared__ float sP[256];
    sP[t] = pv;
    __syncthreads();
    int c0 = b * 32;
    const float* W = nullptr; float* dst = nullptr;
    if (c0 >= 64 && c0 < 960) { W = gin_wih;  dst = GXPin1; }
    else if (c0 >= 960)       { W = ghid_wih; dst = GXPhid1; }
    if (dst) {
        for (int v = t; v < 768; v += 256) {
            int c = v / 24, j = v % 24;
            float a = 0.f;
#pragma unroll
            for (int k = 0; k < 8; ++k) a = fmaf(W[j * 17 + 8 + k], sP[c * 8 + k], a);
            dst[(c0 + c) * 24 + j] = a;
        }
    }
}

// input-layer syn: row r=bid>>2 (<64), cols 64..1024. TICK1 zero-fills inactive.
template <int TICK>
__global__ void __launch_bounds__(256, 4)
k_syn_in(const int* __restrict__ A, const float* __restrict__ hidden0,
         const float* __restrict__ P, float* __restrict__ PH,
         float* __restrict__ Uin, const float* __restrict__ Utop,
         const float* __restrict__ Uout, const float* __restrict__ GXP,
         const float* __restrict__ Wih, const float* __restrict__ Whh,
         const float* __restrict__ Bih, const float* __restrict__ Bhh,
         const float* __restrict__ reward, const float* __restrict__ lr)
{
    int r = blockIdx.x >> 2;
    SYN_STAGE(r);
    int n = 64 + ((blockIdx.x & 3) << 8) + threadIdx.x;
    if (n >= NN) return;
    int e = (r * NN + n) * 8;
    if (!A[r * NN + n]) {
        if (TICK == 1) { f32x8 z{}; st8(PH + e, z); }
        return;
    }
    f32x8 h;
    if (TICK == 1) {
        h = ld8(hidden0 + e);
    } else {
        const float* src = Uin + e;
        if (A[(960 + r) * NN + n])     src = Uout + e;
        else if (A[(64 + r) * NN + n]) src = Utop + e;
        h = ld8(src);
    }
    const float* gxp = GXP + n * 24;
    f32x8 upd = gru_core(sWH, sGX, sBhh, ld8(gxp), ld8(gxp + 8), ld8(gxp + 16), h, lr[0]);
    f32x8 pre = ld8(P + r * 8);
    st8(PH + e, upd * pre);
    if (TICK == 1) st8(Uin + e, upd);
}

// hidden syn tick1, TILED: grid (15 coltiles, 56 rowtiles), 16 rows x 64 cols per block.
// ct 0..13: cols 64..960 -> accumulate Spart (rt>=4), PH write only for l<64 active.
// ct 14   : cols 960..1024 -> PH (l<64: skip-if-inactive, l>=64: val-or-zero) + Urt.
__global__ void __launch_bounds__(256, 4)
k_syn_hid1(const int* __restrict__ A, const float* __restrict__ hidden0,
           const float* __restrict__ P, float* __restrict__ PH,
           float* __restrict__ Utop, float* __restrict__ Urt,
           float* __restrict__ Spart, const float* __restrict__ GXP,
           const float* __restrict__ Wih, const float* __restrict__ Whh,
           const float* __restrict__ Bih, const float* __restrict__ Bhh,
           const float* __restrict__ reward, const float* __restrict__ lr)
{
    int ct = blockIdx.x, rt = blockIdx.y;
    int cbase = 64 + ct * 64;
    __shared__ float sWH[24][8];
    __shared__ float sBhh[24];
    __shared__ __align__(32) float sGX[16][24];
    __shared__ __align__(32) float sPre[16][8];
    int t = threadIdx.x;
    if (t < 192) { int j = t >> 3, k = t & 7; sWH[j][k] = Whh[j * 8 + k]; }
    else if (t < 216) sBhh[t - 192] = Bhh[t - 192];
    if (t < 128) { int rr = t >> 3, k = t & 7; sPre[rr][k] = P[(64 + rt * 16 + rr) * 8 + k]; }
    for (int v = t; v < 384; v += 256) {
        int rr = v / 24, j = v % 24;
        float a = Bih[j] + Wih[j * 17 + 16] * reward[0];
#pragma unroll
        for (int k = 0; k < 8; ++k)
            a = fmaf(Wih[j * 17 + k], P[(64 + rt * 16 + rr) * 8 + k], a);
        sGX[rr][j] = a;
    }
    __syncthreads();
    int cc = t & 63, rg = t >> 6;
    int n = cbase + cc;
    const float* gxp = GXP + n * 24;
    f32x8 gr = ld8(gxp), gz = ld8(gxp + 8), gn = ld8(gxp + 16);
    float lrv = lr[0];
    f32x8 acc{};
#pragma unroll
    for (int rr2 = 0; rr2 < 4; ++rr2) {
        int rr = rg * 4 + rr2;
        int l = rt * 16 + rr;
        int e = (l * NN + n) * 8;
        bool act = A[(64 + l) * NN + n] != 0;
        f32x8 out{};
        if (act) {
            f32x8 h = ld8(hidden0 + ((64 + l) * NN + n) * 8);
            f32x8 upd = gru_core(sWH, sGX[rr], sBhh, gr, gz, gn, h, lrv);
            f32x8 pre = ld8(&sPre[rr][0]);
            out = upd * pre;
            if (l < 64) { st8(PH + e, out); st8(Utop + e, upd); }
            else if (ct == 14) st8(PH + e, out);
            if (ct == 14) st8(Urt + (l * 64 + cc) * 8, upd);
        } else if (ct == 14 && l >= 64) {
            st8(PH + e, out);                      // zero
        }
        acc += out;
    }
    if (ct < 14) {
        __shared__ float sRed[4][64][8];
        st8(&sRed[rg][cc][0], acc);
        __syncthreads();
        if (rt >= 4) {
            for (int v = t; v < 512; v += 256) {
                int col = v >> 3, d = v & 7;
                float s = sRed[0][col][d] + sRed[1][col][d] + sRed[2][col][d] + sRed[3][col][d];
                Spart[(rt * 896 + (cbase - 64) + col) * 8 + d] = s;
            }
        }
    }
}

// output syn tick1: row 960+l, writes PH rows l<64; skip-if-inactive.
__global__ void __launch_bounds__(256, 4)
k_syn_out(const int* __restrict__ A, const float* __restrict__ hidden0,
          const float* __restrict__ P, float* __restrict__ PH,
          float* __restrict__ Uout, const float* __restrict__ GXP,
          const float* __restrict__ Wih, const float* __restrict__ Whh,
          const float* __restrict__ Bih, const float* __restrict__ Bhh,
          const float* __restrict__ reward, const float* __restrict__ lr)
{
    int l = blockIdx.x >> 2;
    SYN_STAGE(960 + l);
    int n = 64 + ((blockIdx.x & 3) << 8) + threadIdx.x;
    if (n >= NN) return;
    if (!A[(960 + l) * NN + n]) return;
    f32x8 h = ld8(hidden0 + ((960 + l) * NN + n) * 8);
    const float* gxp = GXP + n * 24;
    f32x8 upd = gru_core(sWH, sGX, sBhh, ld8(gxp), ld8(gxp + 8), ld8(gxp + 16), h, lr[0]);
    f32x8 pre = ld8(P + (960 + l) * 8);
    int e = (l * NN + n) * 8;
    st8(PH + e, upd * pre);
    st8(Uout + e, upd);
}

// hidden syn tick2: rows 0..896, cols 960..1024 only; skip-if-inactive. 4 rows/block.
__global__ void __launch_bounds__(256, 4)
k_syn_hid2(const int* __restrict__ A, const float* __restrict__ hidden0,
           const float* __restrict__ P, float* __restrict__ PH,
           const float* __restrict__ Urt, const float* __restrict__ GXP,
           const float* __restrict__ Wih, const float* __restrict__ Whh,
           const float* __restrict__ Bih, const float* __restrict__ Bhh,
           const float* __restrict__ reward, const float* __restrict__ lr)
{
    __shared__ float sWH[24][8]; __shared__ float sBhh[24]; __shared__ float sGX4[4][24];
    int t = threadIdx.x;
    if (t < 192) { int j = t >> 3, k = t & 7; sWH[j][k] = Whh[j * 8 + k]; }
    else if (t < 216) sBhh[t - 192] = Bhh[t - 192];
    if (t < 96) {
        int rr = t / 24, j = t % 24;
        int l = blockIdx.x * 4 + rr;
        float a = Bih[j] + Wih[j * 17 + 16] * reward[0];
#pragma unroll
        for (int k = 0; k < 8; ++k) a = fmaf(Wih[j * 17 + k], P[(64 + l) * 8 + k], a);
        sGX4[rr][j] = a;
    }
    __syncthreads();
    int rr = t >> 6, nn = t & 63;
    int l = blockIdx.x * 4 + rr, n = 960 + nn;
    if (!A[(64 + l) * NN + n]) return;
    const float* hp = (l < 832 && A[(128 + l) * NN + n]) ? (Urt + ((64 + l) * 64 + nn) * 8)
                                                         : (hidden0 + ((64 + l) * NN + n) * 8);
    f32x8 h = ld8(hp);
    const float* gxp = GXP + n * 24;
    f32x8 upd = gru_core(sWH, sGX4[rr], sBhh, ld8(gxp), ld8(gxp + 8), ld8(gxp + 16), h, lr[0]);
    f32x8 pre = ld8(P + (64 + l) * 8);
    st8(PH + (l * NN + n) * 8, upd * pre);
}

// tick1 hidden neuron: sum PH rows 0..64, cols 64..960; fused neuron + 3x GXP production.
__global__ void __launch_bounds__(256)
k_sum_hid1(const float* __restrict__ PH, float* __restrict__ P,
           const float* __restrict__ W, const float* __restrict__ b,
           float* __restrict__ GXPhid1, float* __restrict__ GXPout,
           float* __restrict__ GXPin2,
           const float* __restrict__ ghid_wih, const float* __restrict__ gout_wih,
           const float* __restrict__ gin_wih)
{
    int t = threadIdx.x;
    int c0 = 64 + blockIdx.x * 32;
    int base = c0 * 8 + t;
    float acc = 0.f;
    for (int r = 0; r < 64; ++r) acc += PH[r * 8192 + base];
    __shared__ float sS[256];
    sS[t] = acc; __syncthreads();
    int j = t & 7;
    float z = b[j];
#pragma unroll
    for (int d = 0; d < 8; ++d) z = fmaf(sS[(t & ~7) | d], W[j * 8 + d], z);
    float pv = tanhf(z);
    P[base] = pv;
    __shared__ float sP[256];
    sP[t] = pv; __syncthreads();
    for (int v = t; v < 768; v += 256) {
        int c = v / 24, jj = v % 24;
        float a1 = 0.f, a2 = 0.f, a3 = 0.f;
#pragma unroll
        for (int k = 0; k < 8; ++k) {
            float p = sP[c * 8 + k];
            a1 = fmaf(ghid_wih[jj * 17 + 8 + k], p, a1);
            a2 = fmaf(gout_wih[jj * 17 + 8 + k], p, a2);
            a3 = fmaf(gin_wih [jj * 17 + 8 + k], p, a3);
        }
        int o = (c0 + c) * 24 + jj;
        GXPhid1[o] = a1; GXPout[o] = a2; GXPin2[o] = a3;
    }
}

// tick2 hidden neuron: PH rows 0..64 (current) + Spart row-tiles 4..55.
__global__ void __launch_bounds__(256)
k_sum_hid2(const float* __restrict__ PH, const float* __restrict__ Spart,
           float* __restrict__ P, const float* __restrict__ W,
           const float* __restrict__ b)
{
    int t = threadIdx.x;
    int c0 = 64 + blockIdx.x * 32;
    int base = c0 * 8 + t;
    float acc = 0.f;
    for (int r = 0; r < 64; ++r) acc += PH[r * 8192 + base];
    const float* sp = Spart + (c0 - 64) * 8 + t;
    for (int rt = 4; rt < 56; ++rt) acc += sp[rt * 7168];
    __shared__ float sS[256];
    sS[t] = acc; __syncthreads();
    int j = t & 7;
    float z = b[j];
#pragma unroll
    for (int d = 0; d < 8; ++d) z = fmaf(sS[(t & ~7) | d], W[j * 8 + d], z);
    P[base] = tanhf(z);
}

// 896-row column sum + neuron over cols 960.. (8 cols/block), optional GXP production.
template <bool DO_GXP>
__global__ void __launch_bounds__(512)
k_sumN(const float* __restrict__ PH, float* __restrict__ P,
       const float* __restrict__ W, const float* __restrict__ b,
       int col0, float* __restrict__ GXPdst, const float* __restrict__ gWih)
{
    int t = threadIdx.x;
    int col = (t >> 3) & 7, dim = t & 7, chunk = t >> 6;
    int gc0 = col0 + blockIdx.x * 8;
    float acc = 0.f;
    int base = (gc0 + col) * 8 + dim;
    for (int r = chunk * 112; r < chunk * 112 + 112; ++r) acc += PH[r * 8192 + base];
    __shared__ float sA[8][64];
    sA[chunk][(col << 3) | dim] = acc;
    __syncthreads();
    __shared__ float sS[64];
    if (t < 64) {
        float s = 0.f;
#pragma unroll
        for (int c = 0; c < 8; ++c) s += sA[c][t];
        sS[t] = s;
    }
    __syncthreads();
    __shared__ float sPn[64];
    if (t < 64) {
        int cl = t >> 3, j = t & 7;
        float z = b[j];
#pragma unroll
        for (int d = 0; d < 8; ++d) z = fmaf(sS[(cl << 3) | d], W[j * 8 + d], z);
        float pv = tanhf(z);
        P[(gc0 + cl) * 8 + j] = pv;
        sPn[t] = pv;
    }
    __syncthreads();
    if (DO_GXP && t < 192) {
        int c = t / 24, j = t % 24;
        float a = 0.f;
#pragma unroll
        for (int k = 0; k < 8; ++k) a = fmaf(gWih[j * 17 + 8 + k], sPn[c * 8 + k], a);
        GXPdst[(gc0 + c) * 24 + j] = a;
    }
}

__global__ void __launch_bounds__(64)
k_argmax(const float* __restrict__ P, float* __restrict__ out)
{
    __shared__ float v[64];
    int t = threadIdx.x;
    v[t] = P[(960 + t) * 8];
    __syncthreads();
    if (t == 0) {
        int best = 0; float bv = v[0];
        for (int j = 1; j < 64; ++j)
            if (v[j] > bv) { bv = v[j]; best = j; }   // strict > = first-index tie-break
        out[0] = (float)best;
    }
}

extern "C" void kernel_launch(void* const* d_in, const int* in_sizes, int n_in,
                              void* d_out, int out_size, void* d_ws, size_t ws_size,
                              hipStream_t stream)
{
    const float* obs      = (const float*)d_in[0];
    const float* reward   = (const float*)d_in[1];
    const int*   A        = (const int*)d_in[2];
    const float* hidden0  = (const float*)d_in[3];
    const float* post0    = (const float*)d_in[4];
    const float* lr       = (const float*)d_in[5];
    const float* fc_in_w  = (const float*)d_in[6];
    const float* fc_in_b  = (const float*)d_in[7];
    const float* fc_hid_w = (const float*)d_in[8];
    const float* fc_hid_b = (const float*)d_in[9];
    const float* fc_out_w = (const float*)d_in[10];
    const float* fc_out_b = (const float*)d_in[11];
    const float* gin_wih  = (const float*)d_in[12];
    const float* gin_whh  = (const float*)d_in[13];
    const float* gin_bih  = (const float*)d_in[14];
    const float* gin_bhh  = (const float*)d_in[15];
    const float* ghid_wih = (const float*)d_in[16];
    const float* ghid_whh = (const float*)d_in[17];
    const float* ghid_bih = (const float*)d_in[18];
    const float* ghid_bhh = (const float*)d_in[19];
    const float* gout_wih = (const float*)d_in[20];
    const float* gout_whh = (const float*)d_in[21];
    const float* gout_bih = (const float*)d_in[22];
    const float* gout_bhh = (const float*)d_in[23];

    float* ws      = (float*)d_ws;
    float* PH      = ws;
    float* Uin     = ws + 7340032;
    float* Utop    = Uin + 524288;
    float* Urt     = Utop + 524288;
    float* Uout    = Urt + 458752;
    float* P       = Uout + 524288;
    float* GXPin1  = P + 8192;
    float* GXPhid1 = GXPin1 + 24576;
    float* GXPout  = GXPhid1 + 24576;
    float* GXPin2  = GXPout + 24576;
    float* GXPhid2 = GXPin2 + 24576;
    float* Spart   = GXPhid2 + 24576;

    k_prep<<<32, 256, 0, stream>>>(obs, fc_in_w, fc_in_b, post0, P,
                                   GXPin1, GXPhid1, gin_wih, ghid_wih);

    // ---- tick 1 ----
    k_syn_in<1><<<256, 256, 0, stream>>>(A, hidden0, P, PH, Uin, Utop, Uout, GXPin1,
                                         gin_wih, gin_whh, gin_bih, gin_bhh, reward, lr);
    k_sum_hid1<<<28, 256, 0, stream>>>(PH, P, fc_hid_w, fc_hid_b,
                                       GXPhid1, GXPout, GXPin2,
                                       ghid_wih, gout_wih, gin_wih);
    k_syn_hid1<<<dim3(15, 56), 256, 0, stream>>>(A, hidden0, P, PH, Utop, Urt, Spart,
                                                 GXPhid1, ghid_wih, ghid_whh, ghid_bih,
                                                 ghid_bhh, reward, lr);
    k_sumN<true><<<8, 512, 0, stream>>>(PH, P, fc_out_w, fc_out_b, 960, GXPhid2, ghid_wih);
    k_syn_out<<<256, 256, 0, stream>>>(A, hidden0, P, PH, Uout, GXPout,
                                       gout_wih, gout_whh, gout_bih, gout_bhh, reward, lr);

    // ---- tick 2 (input-neuron update identical to tick1 -> skipped; out-syn dead) ----
    k_syn_in<2><<<256, 256, 0, stream>>>(A, hidden0, P, PH, Uin, Utop, Uout, GXPin2,
                                         gin_wih, gin_whh, gin_bih, gin_bhh, reward, lr);
    k_sum_hid2<<<28, 256, 0, stream>>>(PH, Spart, P, fc_hid_w, fc_hid_b);
    k_syn_hid2<<<224, 256, 0, stream>>>(A, hidden0, P, PH, Urt, GXPhid2,
                                        ghid_wih, ghid_whh, ghid_bih, ghid_bhh, reward, lr);
    k_sumN<false><<<8, 512, 0, stream>>>(PH, P, fc_out_w, fc_out_b, 960, nullptr, nullptr);

    k_argmax<<<1, 64, 0, stream>>>(P, (float*)d_out);
}

// Round 8
// 85.170 us; speedup vs baseline: 1.3804x; 1.3804x over previous
//
#include <hip/hip_runtime.h>

#define NN 1024

typedef float f32x8 __attribute__((ext_vector_type(8)));

// ---------------- workspace layout (floats) ----------------
// PH     : [896][1024][8] @ 0        (7340032)  rows>=64 x cols 64..960 NEVER touched
// Uin    : [64][1024][8]  @ 7340032  (524288)
// Utop   : [64][1024][8]  @ 7864320  (524288)
// Urt    : [896][64][8]   @ 8388608  (458752)
// Uout   : [64][1024][8]  @ 8847360  (524288)
// P      : [1024][8]      @ 9371648  (8192)
// GXPin1 : [1024][24]     @ 9379840  gin  over P0
// GXPhid1: [1024][24]     @ 9404416  ghid over P1 (+post0 tail)
// GXPout : [1024][24]     @ 9428992  gout over P2
// GXPin2 : [1024][24]     @ 9453568  gin  over P2
// GXPhid2: [1024][24]     @ 9478144  ghid over P3 (cols 960..)
// Spart  : [224][896][8]  @ 9502720  (1605632) hid1 4-row-tile partials (rt>=16 used)

__device__ __forceinline__ float sigmoid_f(float x)
{
    return __fdividef(1.f, 1.f + __expf(-x));
}
__device__ __forceinline__ float tanh_f(float x)
{
    float ax = fabsf(x);
    float e  = __expf(-2.f * ax);
    float t  = __fdividef(1.f - e, 1.f + e);
    return copysignf(t, x);
}
__device__ __forceinline__ f32x8 ld8(const float* __restrict__ p) { return *(const f32x8*)p; }
__device__ __forceinline__ void st8(float* __restrict__ p, f32x8 v) { *(f32x8*)p = v; }

// gx = sGX[j] (row part) + g{r,z,n}[d] (col part, in regs); gh = sBhh[j] + Whh[j]·h
__device__ __forceinline__ f32x8 gru_core(const float (*__restrict__ sWH)[8],
                                          const float* __restrict__ sGX,
                                          const float* __restrict__ sBhh,
                                          f32x8 gr, f32x8 gz, f32x8 gn,
                                          f32x8 h, float lr)
{
    f32x8 upd;
#pragma unroll
    for (int d = 0; d < 8; ++d) {
        float hr = sBhh[d], hz = sBhh[8 + d], hn = sBhh[16 + d];
#pragma unroll
        for (int k = 0; k < 8; ++k) {
            hr = fmaf(sWH[d][k],      h[k], hr);
            hz = fmaf(sWH[8 + d][k],  h[k], hz);
            hn = fmaf(sWH[16 + d][k], h[k], hn);
        }
        float r  = sigmoid_f(sGX[d] + gr[d] + hr);
        float z  = sigmoid_f(sGX[8 + d] + gz[d] + hz);
        float nv = tanh_f(fmaf(r, hn, sGX[16 + d] + gn[d]));
        float g  = (1.f - z) * nv + z * h[d];
        upd[d] = fmaf(g, lr, h[d]);
    }
    return upd;
}

#define SYN_STAGE(PREROW)                                                               \
    __shared__ float sWH[24][8]; __shared__ float sGX[24]; __shared__ float sBhh[24];   \
    { int t_ = threadIdx.x;                                                             \
      if (t_ < 192) { int j = t_ >> 3, k = t_ & 7; sWH[j][k] = Whh[j * 8 + k]; }        \
      else if (t_ < 216) { int j = t_ - 192;                                            \
        float a = Bih[j] + Wih[j * 17 + 16] * reward[0];                                \
        _Pragma("unroll") for (int k = 0; k < 8; ++k)                                   \
            a = fmaf(Wih[j * 17 + k], P[(PREROW) * 8 + k], a);                          \
        sGX[j] = a; sBhh[j] = Bhh[j]; }                                                 \
      __syncthreads(); }

// P init + GXPin1 (gin over P0) + GXPhid1 tail (ghid over post0, cols 960..)
__global__ void __launch_bounds__(256)
k_prep(const float* __restrict__ obs, const float* __restrict__ fiw,
       const float* __restrict__ fib, const float* __restrict__ post0,
       float* __restrict__ P, float* __restrict__ GXPin1, float* __restrict__ GXPhid1,
       const float* __restrict__ gin_wih, const float* __restrict__ ghid_wih)
{
    int t = threadIdx.x, b = blockIdx.x;
    int gid = b * 256 + t;
    float pv;
    if (gid < 512) {
        int i = gid >> 3, j = gid & 7;
        float rs = 0.f;
#pragma unroll
        for (int d = 0; d < 8; ++d) rs += fiw[j * 8 + d];
        pv = tanhf(obs[i] * rs + fib[j]);
    } else {
        pv = post0[gid];
    }
    P[gid] = pv;
    __shared__ float sP[256];
    sP[t] = pv;
    __syncthreads();
    int c0 = b * 32;
    const float* W = nullptr; float* dst = nullptr;
    if (c0 >= 64 && c0 < 960) { W = gin_wih;  dst = GXPin1; }
    else if (c0 >= 960)       { W = ghid_wih; dst = GXPhid1; }
    if (dst) {
        for (int v = t; v < 768; v += 256) {
            int c = v / 24, j = v % 24;
            float a = 0.f;
#pragma unroll
            for (int k = 0; k < 8; ++k) a = fmaf(W[j * 17 + 8 + k], sP[c * 8 + k], a);
            dst[(c0 + c) * 24 + j] = a;
        }
    }
}

// input-layer syn: row r=bid>>2 (<64), cols 64..1024. TICK1 zero-fills inactive.
template <int TICK>
__global__ void __launch_bounds__(256, 4)
k_syn_in(const int* __restrict__ A, const float* __restrict__ hidden0,
         const float* __restrict__ P, float* __restrict__ PH,
         float* __restrict__ Uin, const float* __restrict__ Utop,
         const float* __restrict__ Uout, const float* __restrict__ GXP,
         const float* __restrict__ Wih, const float* __restrict__ Whh,
         const float* __restrict__ Bih, const float* __restrict__ Bhh,
         const float* __restrict__ reward, const float* __restrict__ lr)
{
    int r = blockIdx.x >> 2;
    SYN_STAGE(r);
    int n = 64 + ((blockIdx.x & 3) << 8) + threadIdx.x;
    if (n >= NN) return;
    int e = (r * NN + n) * 8;
    if (!A[r * NN + n]) {
        if (TICK == 1) { f32x8 z{}; st8(PH + e, z); }
        return;
    }
    f32x8 h;
    if (TICK == 1) {
        h = ld8(hidden0 + e);
    } else {
        const float* src = Uin + e;
        if (A[(960 + r) * NN + n])     src = Uout + e;
        else if (A[(64 + r) * NN + n]) src = Utop + e;
        h = ld8(src);
    }
    const float* gxp = GXP + n * 24;
    f32x8 upd = gru_core(sWH, sGX, sBhh, ld8(gxp), ld8(gxp + 8), ld8(gxp + 16), h, lr[0]);
    f32x8 pre = ld8(P + r * 8);
    st8(PH + e, upd * pre);
    if (TICK == 1) st8(Uin + e, upd);
}

// hidden syn tick1, light tiles: grid (15 coltiles, 224 rowtiles), 4 rows x 64 cols,
// ONE GRU per thread (no unroll -> no spill).
// ct 0..13 (cols 64..960): accumulate 4-row partial into Spart (rt>=16);
//   l<64 additionally writes PH+Utop where active.
// ct 14 (cols 960..1024): PH (l<64 skip-if-inactive, l>=64 val-or-zero) + Urt.
__global__ void __launch_bounds__(256, 4)
k_syn_hid1(const int* __restrict__ A, const float* __restrict__ hidden0,
           const float* __restrict__ P, float* __restrict__ PH,
           float* __restrict__ Utop, float* __restrict__ Urt,
           float* __restrict__ Spart, const float* __restrict__ GXP,
           const float* __restrict__ Wih, const float* __restrict__ Whh,
           const float* __restrict__ Bih, const float* __restrict__ Bhh,
           const float* __restrict__ reward, const float* __restrict__ lr)
{
    int ct = blockIdx.x, rt = blockIdx.y;
    __shared__ float sWH[24][8];
    __shared__ float sBhh[24];
    __shared__ float sGX4[4][24];
    __shared__ __align__(32) float sPre[4][8];
    __shared__ __align__(32) float sRed[4][64][8];
    int t = threadIdx.x;
    if (t < 192) { int j = t >> 3, k = t & 7; sWH[j][k] = Whh[j * 8 + k]; }
    else if (t < 216) sBhh[t - 192] = Bhh[t - 192];
    else if (t >= 224) { int rr = (t - 224) >> 3, k = t & 7; sPre[rr][k] = P[(64 + rt * 4 + rr) * 8 + k]; }
    if (t < 96) {
        int rr = t / 24, j = t % 24;
        float a = Bih[j] + Wih[j * 17 + 16] * reward[0];
#pragma unroll
        for (int k = 0; k < 8; ++k)
            a = fmaf(Wih[j * 17 + k], P[(64 + rt * 4 + rr) * 8 + k], a);
        sGX4[rr][j] = a;
    }
    __syncthreads();
    int rr = t >> 6, cc = t & 63;
    int l = rt * 4 + rr;
    int n = (ct < 14) ? (64 + ct * 64 + cc) : (960 + cc);
    int e = (l * NN + n) * 8;
    bool act = A[(64 + l) * NN + n] != 0;
    f32x8 out{};
    if (act) {
        f32x8 h = ld8(hidden0 + ((64 + l) * NN + n) * 8);
        const float* gxp = GXP + n * 24;
        f32x8 upd = gru_core(sWH, sGX4[rr], sBhh, ld8(gxp), ld8(gxp + 8), ld8(gxp + 16),
                             h, lr[0]);
        f32x8 pre = ld8(&sPre[rr][0]);
        out = upd * pre;
        if (l < 64) { st8(PH + e, out); st8(Utop + e, upd); }
        else if (ct == 14) st8(PH + e, out);
        if (ct == 14) st8(Urt + (l * 64 + cc) * 8, upd);
    } else if (ct == 14 && l >= 64) {
        st8(PH + e, out);                     // zero
    }
    if (ct < 14 && rt >= 16) {
        st8(&sRed[rr][cc][0], out);
        __syncthreads();
        for (int v = t; v < 512; v += 256) {
            int col = v >> 3, d = v & 7;
            Spart[(rt * 896 + ct * 64 + col) * 8 + d] =
                sRed[0][col][d] + sRed[1][col][d] + sRed[2][col][d] + sRed[3][col][d];
        }
    }
}

// output syn tick1: row 960+l, writes PH rows l<64; skip-if-inactive.
__global__ void __launch_bounds__(256, 4)
k_syn_out(const int* __restrict__ A, const float* __restrict__ hidden0,
          const float* __restrict__ P, float* __restrict__ PH,
          float* __restrict__ Uout, const float* __restrict__ GXP,
          const float* __restrict__ Wih, const float* __restrict__ Whh,
          const float* __restrict__ Bih, const float* __restrict__ Bhh,
          const float* __restrict__ reward, const float* __restrict__ lr)
{
    int l = blockIdx.x >> 2;
    SYN_STAGE(960 + l);
    int n = 64 + ((blockIdx.x & 3) << 8) + threadIdx.x;
    if (n >= NN) return;
    if (!A[(960 + l) * NN + n]) return;
    f32x8 h = ld8(hidden0 + ((960 + l) * NN + n) * 8);
    const float* gxp = GXP + n * 24;
    f32x8 upd = gru_core(sWH, sGX, sBhh, ld8(gxp), ld8(gxp + 8), ld8(gxp + 16), h, lr[0]);
    f32x8 pre = ld8(P + (960 + l) * 8);
    int e = (l * NN + n) * 8;
    st8(PH + e, upd * pre);
    st8(Uout + e, upd);
}

// hidden syn tick2: rows 0..896, cols 960..1024 only; skip-if-inactive. 4 rows/block.
__global__ void __launch_bounds__(256, 4)
k_syn_hid2(const int* __restrict__ A, const float* __restrict__ hidden0,
           const float* __restrict__ P, float* __restrict__ PH,
           const float* __restrict__ Urt, const float* __restrict__ GXP,
           const float* __restrict__ Wih, const float* __restrict__ Whh,
           const float* __restrict__ Bih, const float* __restrict__ Bhh,
           const float* __restrict__ reward, const float* __restrict__ lr)
{
    __shared__ float sWH[24][8]; __shared__ float sBhh[24]; __shared__ float sGX4[4][24];
    int t = threadIdx.x;
    if (t < 192) { int j = t >> 3, k = t & 7; sWH[j][k] = Whh[j * 8 + k]; }
    else if (t < 216) sBhh[t - 192] = Bhh[t - 192];
    if (t < 96) {
        int rr = t / 24, j = t % 24;
        int l = blockIdx.x * 4 + rr;
        float a = Bih[j] + Wih[j * 17 + 16] * reward[0];
#pragma unroll
        for (int k = 0; k < 8; ++k) a = fmaf(Wih[j * 17 + k], P[(64 + l) * 8 + k], a);
        sGX4[rr][j] = a;
    }
    __syncthreads();
    int rr = t >> 6, nn = t & 63;
    int l = blockIdx.x * 4 + rr, n = 960 + nn;
    if (!A[(64 + l) * NN + n]) return;
    const float* hp = (l < 832 && A[(128 + l) * NN + n]) ? (Urt + ((64 + l) * 64 + nn) * 8)
                                                         : (hidden0 + ((64 + l) * NN + n) * 8);
    f32x8 h = ld8(hp);
    const float* gxp = GXP + n * 24;
    f32x8 upd = gru_core(sWH, sGX4[rr], sBhh, ld8(gxp), ld8(gxp + 8), ld8(gxp + 16), h, lr[0]);
    f32x8 pre = ld8(P + (64 + l) * 8);
    st8(PH + (l * NN + n) * 8, upd * pre);
}

// tick1 hidden neuron: sum PH rows 0..64, cols 64..960; fused neuron + 3x GXP production.
__global__ void __launch_bounds__(256)
k_sum_hid1(const float* __restrict__ PH, float* __restrict__ P,
           const float* __restrict__ W, const float* __restrict__ b,
           float* __restrict__ GXPhid1, float* __restrict__ GXPout,
           float* __restrict__ GXPin2,
           const float* __restrict__ ghid_wih, const float* __restrict__ gout_wih,
           const float* __restrict__ gin_wih)
{
    int t = threadIdx.x;
    int c0 = 64 + blockIdx.x * 32;
    int base = c0 * 8 + t;
    float acc = 0.f;
    for (int r = 0; r < 64; ++r) acc += PH[r * 8192 + base];
    __shared__ float sS[256];
    sS[t] = acc; __syncthreads();
    int j = t & 7;
    float z = b[j];
#pragma unroll
    for (int d = 0; d < 8; ++d) z = fmaf(sS[(t & ~7) | d], W[j * 8 + d], z);
    float pv = tanhf(z);
    P[base] = pv;
    __shared__ float sP[256];
    sP[t] = pv; __syncthreads();
    for (int v = t; v < 768; v += 256) {
        int c = v / 24, jj = v % 24;
        float a1 = 0.f, a2 = 0.f, a3 = 0.f;
#pragma unroll
        for (int k = 0; k < 8; ++k) {
            float p = sP[c * 8 + k];
            a1 = fmaf(ghid_wih[jj * 17 + 8 + k], p, a1);
            a2 = fmaf(gout_wih[jj * 17 + 8 + k], p, a2);
            a3 = fmaf(gin_wih [jj * 17 + 8 + k], p, a3);
        }
        int o = (c0 + c) * 24 + jj;
        GXPhid1[o] = a1; GXPout[o] = a2; GXPin2[o] = a3;
    }
}

// tick2 hidden neuron: PH rows 0..64 (current) + Spart row-tiles 16..223.
__global__ void __launch_bounds__(256)
k_sum_hid2(const float* __restrict__ PH, const float* __restrict__ Spart,
           float* __restrict__ P, const float* __restrict__ W,
           const float* __restrict__ b)
{
    int t = threadIdx.x;
    int c0 = 64 + blockIdx.x * 32;
    int base = c0 * 8 + t;
    float acc = 0.f;
    for (int r = 0; r < 64; ++r) acc += PH[r * 8192 + base];
    const float* sp = Spart + (c0 - 64) * 8 + t;
    for (int rt = 16; rt < 224; ++rt) acc += sp[rt * 7168];
    __shared__ float sS[256];
    sS[t] = acc; __syncthreads();
    int j = t & 7;
    float z = b[j];
#pragma unroll
    for (int d = 0; d < 8; ++d) z = fmaf(sS[(t & ~7) | d], W[j * 8 + d], z);
    P[base] = tanhf(z);
}

// 896-row column sum + neuron over cols 960.. (8 cols/block), optional GXP production.
template <bool DO_GXP>
__global__ void __launch_bounds__(512)
k_sumN(const float* __restrict__ PH, float* __restrict__ P,
       const float* __restrict__ W, const float* __restrict__ b,
       int col0, float* __restrict__ GXPdst, const float* __restrict__ gWih)
{
    int t = threadIdx.x;
    int col = (t >> 3) & 7, dim = t & 7, chunk = t >> 6;
    int gc0 = col0 + blockIdx.x * 8;
    float acc = 0.f;
    int base = (gc0 + col) * 8 + dim;
    for (int r = chunk * 112; r < chunk * 112 + 112; ++r) acc += PH[r * 8192 + base];
    __shared__ float sA[8][64];
    sA[chunk][(col << 3) | dim] = acc;
    __syncthreads();
    __shared__ float sS[64];
    if (t < 64) {
        float s = 0.f;
#pragma unroll
        for (int c = 0; c < 8; ++c) s += sA[c][t];
        sS[t] = s;
    }
    __syncthreads();
    __shared__ float sPn[64];
    if (t < 64) {
        int cl = t >> 3, j = t & 7;
        float z = b[j];
#pragma unroll
        for (int d = 0; d < 8; ++d) z = fmaf(sS[(cl << 3) | d], W[j * 8 + d], z);
        float pv = tanhf(z);
        P[(gc0 + cl) * 8 + j] = pv;
        sPn[t] = pv;
    }
    __syncthreads();
    if (DO_GXP && t < 192) {
        int c = t / 24, j = t % 24;
        float a = 0.f;
#pragma unroll
        for (int k = 0; k < 8; ++k) a = fmaf(gWih[j * 17 + 8 + k], sPn[c * 8 + k], a);
        GXPdst[(gc0 + c) * 24 + j] = a;
    }
}

__global__ void __launch_bounds__(64)
k_argmax(const float* __restrict__ P, float* __restrict__ out)
{
    __shared__ float v[64];
    int t = threadIdx.x;
    v[t] = P[(960 + t) * 8];
    __syncthreads();
    if (t == 0) {
        int best = 0; float bv = v[0];
        for (int j = 1; j < 64; ++j)
            if (v[j] > bv) { bv = v[j]; best = j; }   // strict > = first-index tie-break
        out[0] = (float)best;
    }
}

extern "C" void kernel_launch(void* const* d_in, const int* in_sizes, int n_in,
                              void* d_out, int out_size, void* d_ws, size_t ws_size,
                              hipStream_t stream)
{
    const float* obs      = (const float*)d_in[0];
    const float* reward   = (const float*)d_in[1];
    const int*   A        = (const int*)d_in[2];
    const float* hidden0  = (const float*)d_in[3];
    const float* post0    = (const float*)d_in[4];
    const float* lr       = (const float*)d_in[5];
    const float* fc_in_w  = (const float*)d_in[6];
    const float* fc_in_b  = (const float*)d_in[7];
    const float* fc_hid_w = (const float*)d_in[8];
    const float* fc_hid_b = (const float*)d_in[9];
    const float* fc_out_w = (const float*)d_in[10];
    const float* fc_out_b = (const float*)d_in[11];
    const float* gin_wih  = (const float*)d_in[12];
    const float* gin_whh  = (const float*)d_in[13];
    const float* gin_bih  = (const float*)d_in[14];
    const float* gin_bhh  = (const float*)d_in[15];
    const float* ghid_wih = (const float*)d_in[16];
    const float* ghid_whh = (const float*)d_in[17];
    const float* ghid_bih = (const float*)d_in[18];
    const float* ghid_bhh = (const float*)d_in[19];
    const float* gout_wih = (const float*)d_in[20];
    const float* gout_whh = (const float*)d_in[21];
    const float* gout_bih = (const float*)d_in[22];
    const float* gout_bhh = (const float*)d_in[23];

    float* ws      = (float*)d_ws;
    float* PH      = ws;
    float* Uin     = ws + 7340032;
    float* Utop    = Uin + 524288;
    float* Urt     = Utop + 524288;
    float* Uout    = Urt + 458752;
    float* P       = Uout + 524288;
    float* GXPin1  = P + 8192;
    float* GXPhid1 = GXPin1 + 24576;
    float* GXPout  = GXPhid1 + 24576;
    float* GXPin2  = GXPout + 24576;
    float* GXPhid2 = GXPin2 + 24576;
    float* Spart   = GXPhid2 + 24576;

    k_prep<<<32, 256, 0, stream>>>(obs, fc_in_w, fc_in_b, post0, P,
                                   GXPin1, GXPhid1, gin_wih, ghid_wih);

    // ---- tick 1 ----
    k_syn_in<1><<<256, 256, 0, stream>>>(A, hidden0, P, PH, Uin, Utop, Uout, GXPin1,
                                         gin_wih, gin_whh, gin_bih, gin_bhh, reward, lr);
    k_sum_hid1<<<28, 256, 0, stream>>>(PH, P, fc_hid_w, fc_hid_b,
                                       GXPhid1, GXPout, GXPin2,
                                       ghid_wih, gout_wih, gin_wih);
    k_syn_hid1<<<dim3(15, 224), 256, 0, stream>>>(A, hidden0, P, PH, Utop, Urt, Spart,
                                                  GXPhid1, ghid_wih, ghid_whh, ghid_bih,
                                                  ghid_bhh, reward, lr);
    k_sumN<true><<<8, 512, 0, stream>>>(PH, P, fc_out_w, fc_out_b, 960, GXPhid2, ghid_wih);
    k_syn_out<<<256, 256, 0, stream>>>(A, hidden0, P, PH, Uout, GXPout,
                                       gout_wih, gout_whh, gout_bih, gout_bhh, reward, lr);

    // ---- tick 2 (input-neuron update identical to tick1 -> skipped; out-syn dead) ----
    k_syn_in<2><<<256, 256, 0, stream>>>(A, hidden0, P, PH, Uin, Utop, Uout, GXPin2,
                                         gin_wih, gin_whh, gin_bih, gin_bhh, reward, lr);
    k_sum_hid2<<<28, 256, 0, stream>>>(PH, Spart, P, fc_hid_w, fc_hid_b);
    k_syn_hid2<<<224, 256, 0, stream>>>(A, hidden0, P, PH, Urt, GXPhid2,
                                        ghid_wih, ghid_whh, ghid_bih, ghid_bhh, reward, lr);
    k_sumN<false><<<8, 512, 0, stream>>>(PH, P, fc_out_b ? fc_out_w : fc_out_w, fc_out_b,
                                         960, nullptr, nullptr);

    k_argmax<<<1, 64, 0, stream>>>(P, (float*)d_out);
}